// Round 5
// baseline (71.443 us; speedup 1.0000x reference)
//
#include <hip/hip_runtime.h>

// Lennard-Jones per-edge energy + scatter-sum — no global atomics.
//
// R4 evidence: K1 is latency-bound on the 6.4M random atom_types gathers;
// VGPR_Count=36 (forced by __launch_bounds__(256,6)) killed memory-level
// parallelism. R5: explicit 3-phase K1 (load indices -> issue ALL gathers
// branch-free -> compute), __launch_bounds__(256,4) for ~128 VGPR budget.
//
// Inputs: 0 sigma[16,16] 1 delta[16,16] 2 epsilon[16,16] (f32)
//         3 edge_len[E] 4 edge_cutoff[E] (f32)  5 edge_index[2,E] (int32)
//         6 atom_types[N] (int32)         Output: [N,1] f32.

#define THREADS 256
#define EPT     12            // edges per thread in K1
#define EPB     (THREADS*EPT) // 3072 edges per K1 block
#define BSHIFT  8
#define BSIZE   256           // nodes per bucket
#define MAXBLK  2048
#define MAXBUCKET 512

__device__ __forceinline__ float lj_energy(float sig, float dlt, float eps,
                                           float len, float cut) {
    const float r  = sig / (len - dlt);
    const float r2 = r * r;
    const float x  = r2 * r2 * r2;               // (sig/(len-dlt))^6
    return 2.0f * eps * (x * x - x) * cut;
}

__device__ __forceinline__ void load_tables(const float* __restrict__ sigma,
                                            const float* __restrict__ delta,
                                            const float* __restrict__ epsilon,
                                            float* s_sig, float* s_dlt, float* s_eps,
                                            int t) {
    const int i  = t >> 4;
    const int j  = t & 15;
    const int lo = min(i, j);
    const int hi = max(i, j);
    const int src = lo * 16 + hi;          // sym = triu(p) + triu(p,1).T
    s_sig[t] = fmaxf(sigma[src],   0.0f);  // relu
    s_dlt[t] = fmaxf(delta[src],   0.0f);
    s_eps[t] = fmaxf(epsilon[src], 0.0f);
}

// ---------------- K1: energy + block-local counting sort by bucket ------------
__global__ __launch_bounds__(THREADS, 4) void lj_bin_kernel(
    const float* __restrict__ sigma,
    const float* __restrict__ delta,
    const float* __restrict__ epsilon,
    const float* __restrict__ edge_len,
    const float* __restrict__ edge_cutoff,
    const int*  __restrict__ edge_index,     // [2,E] flat
    const int*  __restrict__ atom_types,     // [N]
    uint32_t* __restrict__ pairs,            // [nblk*EPB] packed (energy|local8)
    uint32_t* __restrict__ aux,              // [nbucket][nblk] count|offset<<16
    int n_edges, int nbucket, int nblk)
{
    __shared__ float s_sig[256], s_dlt[256], s_eps[256];
    __shared__ uint32_t hist[MAXBUCKET];
    __shared__ uint32_t base_[MAXBUCKET];
    __shared__ uint32_t s2[THREADS], sc[THREADS];
    __shared__ uint32_t stage[EPB];

    const int t = threadIdx.x;
    load_tables(sigma, delta, epsilon, s_sig, s_dlt, s_eps, t);
    hist[t] = 0u;
    hist[t + 256] = 0u;

    const int blk     = blockIdx.x;
    const int blkbase = blk * EPB;

    // ---- phase 1: load all indices + len/cut for this thread's 12 edges ----
    int   c_[EPT], o_[EPT];
    float L_[EPT], C_[EPT];
    #pragma unroll
    for (int i = 0; i < EPT / 4; ++i) {
        const int g = blkbase + i * (THREADS * 4) + t * 4;
        if (g + 3 < n_edges) {
            const int4   ctr = *reinterpret_cast<const int4*>(edge_index + g);
            const int4   oth = *reinterpret_cast<const int4*>(edge_index + n_edges + g);
            const float4 len = *reinterpret_cast<const float4*>(edge_len + g);
            const float4 cut = *reinterpret_cast<const float4*>(edge_cutoff + g);
            c_[i*4+0] = ctr.x; c_[i*4+1] = ctr.y; c_[i*4+2] = ctr.z; c_[i*4+3] = ctr.w;
            o_[i*4+0] = oth.x; o_[i*4+1] = oth.y; o_[i*4+2] = oth.z; o_[i*4+3] = oth.w;
            L_[i*4+0] = len.x; L_[i*4+1] = len.y; L_[i*4+2] = len.z; L_[i*4+3] = len.w;
            C_[i*4+0] = cut.x; C_[i*4+1] = cut.y; C_[i*4+2] = cut.z; C_[i*4+3] = cut.w;
        } else {
            #pragma unroll
            for (int k = 0; k < 4; ++k) {
                const int e = g + k;
                const bool v = (e < n_edges);
                c_[i*4+k] = v ? edge_index[e] : -1;
                o_[i*4+k] = v ? edge_index[n_edges + e] : 0;
                L_[i*4+k] = v ? edge_len[e] : 1.0f;
                C_[i*4+k] = v ? edge_cutoff[e] : 0.0f;
            }
        }
    }

    // ---- phase 2: issue ALL atom_types gathers, branch-free (clamped) ----
    int tc[EPT], to[EPT];
    #pragma unroll
    for (int j = 0; j < EPT; ++j) {
        tc[j] = atom_types[max(c_[j], 0)];
        to[j] = atom_types[o_[j]];
    }

    __syncthreads();   // tables + hist ready

    // ---- phase 3: compute, pack, histogram ----
    uint32_t pk[EPT];
    int      bk[EPT];
    #pragma unroll
    for (int j = 0; j < EPT; ++j) {
        if (c_[j] >= 0) {
            const int flat = (tc[j] << 4) | to[j];
            const float e  = lj_energy(s_sig[flat], s_dlt[flat], s_eps[flat],
                                       L_[j], C_[j]);
            pk[j] = (__float_as_uint(e) & ~255u) | (uint32_t)(c_[j] & 255);
            bk[j] = c_[j] >> BSHIFT;
            atomicAdd(&hist[bk[j]], 1u);
        } else {
            bk[j] = -1;
        }
    }
    __syncthreads();

    // exclusive scan of hist[0..511] (256 threads, pair trick)
    s2[t] = hist[2*t] + hist[2*t + 1];
    sc[t] = s2[t];
    for (int off = 1; off < THREADS; off <<= 1) {
        __syncthreads();
        const uint32_t v = (t >= off) ? sc[t - off] : 0u;
        __syncthreads();
        sc[t] += v;
    }
    __syncthreads();
    const uint32_t excl = sc[t] - s2[t];
    base_[2*t]     = excl;
    base_[2*t + 1] = excl + hist[2*t];
    __syncthreads();

    // aux[bucket][blk] = count | offset<<16   (EPB=3072 fits u16)
    for (int bb = t; bb < nbucket; bb += THREADS)
        aux[(size_t)bb * nblk + blk] = hist[bb] | (base_[bb] << 16);
    __syncthreads();

    // reuse hist as scatter cursor
    hist[2*t]     = base_[2*t];
    hist[2*t + 1] = base_[2*t + 1];
    __syncthreads();

    #pragma unroll
    for (int j = 0; j < EPT; ++j) {
        if (bk[j] >= 0) {
            const uint32_t r = atomicAdd(&hist[bk[j]], 1u);
            stage[r] = pk[j];
        }
    }
    __syncthreads();

    const int nval = min(EPB, n_edges - blkbase);
    for (int i = t; i < nval; i += THREADS)
        pairs[(size_t)blk * EPB + i] = stage[i];
}

// ---------------- K2: per-(bucket,chunk) gather + LDS accumulate --------------
// grid = (nbucket, CH). Writes dst[(b*CH + c)*256 + t] (CH==1: dst=out directly).
__global__ __launch_bounds__(THREADS) void lj_gather_kernel(
    const uint32_t* __restrict__ pairs,
    const uint32_t* __restrict__ aux,
    float* __restrict__ dst,
    int nblk, int bpc, long long limit)
{
    __shared__ float acc[4][BSIZE];
    __shared__ uint32_t cof[MAXBLK];

    const int t  = threadIdx.x;
    const int b  = blockIdx.x;
    const int c  = blockIdx.y;
    const int CH = gridDim.y;

    const int lo   = c * bpc;
    const int hi   = min(nblk, lo + bpc);
    const int nrun = hi - lo;

    #pragma unroll
    for (int w = 0; w < 4; ++w) acc[w][t] = 0.0f;
    for (int i = t; i < nrun; i += THREADS)
        cof[i] = aux[(size_t)b * nblk + lo + i];
    __syncthreads();

    const int wave = t >> 6;
    const int lane = t & 63;
    const int grp  = lane >> 3;      // 8 groups of 8 lanes per wave
    const int lig  = lane & 7;
    const int s    = wave * 8 + grp; // 32 parallel run-streams per block

    for (int run = s; run < nrun; run += 32) {
        const uint32_t ce  = cof[run];
        const int cnt = (int)(ce & 0xffffu);
        const int off = (int)(ce >> 16);
        const size_t gbase = (size_t)(lo + run) * EPB + off;
        for (int j = lig; j < cnt; j += 8) {
            const uint32_t p = pairs[gbase + j];
            atomicAdd(&acc[wave][p & 255u], __uint_as_float(p & ~255u));
        }
    }
    __syncthreads();

    const long long idx = ((long long)b * CH + c) * BSIZE + t;
    if (idx < limit)
        dst[idx] = acc[0][t] + acc[1][t] + acc[2][t] + acc[3][t];
}

// ---------------- K3: reduce CH chunk-partials -> out -------------------------
__global__ __launch_bounds__(THREADS) void lj_reduce_kernel(
    const float* __restrict__ partial, float* __restrict__ out,
    int n_nodes, int CH)
{
    const int n = blockIdx.x * THREADS + threadIdx.x;
    if (n < n_nodes) {
        const int b = n >> BSHIFT;
        const int i = n & (BSIZE - 1);
        float s = 0.0f;
        for (int c = 0; c < CH; ++c)
            s += partial[(((size_t)b * CH + c) << BSHIFT) + i];
        out[n] = s;
    }
}

// ---------------- fallback: direct device-scope atomics -----------------------
__global__ __launch_bounds__(THREADS) void lj_scatter_direct(
    const float* __restrict__ sigma,
    const float* __restrict__ delta,
    const float* __restrict__ epsilon,
    const float* __restrict__ edge_len,
    const float* __restrict__ edge_cutoff,
    const int*  __restrict__ edge_index,
    const int*  __restrict__ atom_types,
    float* __restrict__ out,
    int n_edges)
{
    __shared__ float s_sig[256], s_dlt[256], s_eps[256];
    const int t = threadIdx.x;
    load_tables(sigma, delta, epsilon, s_sig, s_dlt, s_eps, t);
    __syncthreads();

    const int base = (blockIdx.x * THREADS + t) * 4;
    if (base >= n_edges) return;
    const int lim = min(base + 4, n_edges);
    for (int e = base; e < lim; ++e) {
        const int ci = edge_index[e];
        const int oi = edge_index[n_edges + e];
        const int flat = (atom_types[ci] << 4) | atom_types[oi];
        const float en = lj_energy(s_sig[flat], s_dlt[flat], s_eps[flat],
                                   edge_len[e], edge_cutoff[e]);
        atomicAdd(out + ci, en);
    }
}

extern "C" void kernel_launch(void* const* d_in, const int* in_sizes, int n_in,
                              void* d_out, int out_size, void* d_ws, size_t ws_size,
                              hipStream_t stream) {
    const float* sigma       = (const float*)d_in[0];
    const float* delta       = (const float*)d_in[1];
    const float* epsilon     = (const float*)d_in[2];
    const float* edge_len    = (const float*)d_in[3];
    const float* edge_cutoff = (const float*)d_in[4];
    const int*   edge_index  = (const int*)d_in[5];
    const int*   atom_types  = (const int*)d_in[6];
    float*       out         = (float*)d_out;

    const int n_edges = in_sizes[3];
    const int n_nodes = in_sizes[6];

    const int nblk    = (n_edges + EPB - 1) / EPB;
    const int nbucket = (n_nodes + BSIZE - 1) / BSIZE;

    const size_t pairs_bytes = (size_t)nblk * EPB * sizeof(uint32_t);
    const size_t aux_bytes   = (size_t)nbucket * nblk * sizeof(uint32_t);
    const size_t need_base   = pairs_bytes + aux_bytes;

    if (nbucket <= MAXBUCKET && nblk <= MAXBLK && ws_size >= need_base) {
        uint32_t* pairs = (uint32_t*)d_ws;
        uint32_t* aux   = (uint32_t*)((char*)d_ws + pairs_bytes);

        // pick chunk count CH by available workspace for partials
        int CH = 1;
        for (int tryCH = 16; tryCH >= 2; tryCH >>= 1) {
            const size_t part = (size_t)nbucket * tryCH * BSIZE * sizeof(float);
            if (ws_size >= need_base + part) { CH = tryCH; break; }
        }

        lj_bin_kernel<<<nblk, THREADS, 0, stream>>>(
            sigma, delta, epsilon, edge_len, edge_cutoff,
            edge_index, atom_types, pairs, aux, n_edges, nbucket, nblk);

        const int bpc = (nblk + CH - 1) / CH;
        if (CH == 1) {
            lj_gather_kernel<<<dim3(nbucket, 1), THREADS, 0, stream>>>(
                pairs, aux, out, nblk, bpc, (long long)n_nodes);
        } else {
            float* partial = (float*)((char*)d_ws + need_base);
            const long long plimit = (long long)nbucket * CH * BSIZE;
            lj_gather_kernel<<<dim3(nbucket, CH), THREADS, 0, stream>>>(
                pairs, aux, partial, nblk, bpc, plimit);
            const int rgrid = (n_nodes + THREADS - 1) / THREADS;
            lj_reduce_kernel<<<rgrid, THREADS, 0, stream>>>(
                partial, out, n_nodes, CH);
        }
    } else {
        hipMemsetAsync(d_out, 0, (size_t)out_size * sizeof(float), stream);
        const int grid = (n_edges + THREADS * 4 - 1) / (THREADS * 4);
        lj_scatter_direct<<<grid, THREADS, 0, stream>>>(
            sigma, delta, epsilon, edge_len, edge_cutoff,
            edge_index, atom_types, out, n_edges);
    }
}